// Round 20
// baseline (39.969 us; speedup 1.0000x reference)
//
#include <hip/hip_runtime.h>
#include <stdint.h>

typedef __attribute__((ext_vector_type(8))) short short8;
typedef __attribute__((ext_vector_type(4))) float f32x4;

#define SEQ 256
#define NH 8

__device__ __forceinline__ uint32_t cvt_pk_bf16(float lo, float hi) {
  uint32_t r;
  asm("v_cvt_pk_bf16_f32 %0, %1, %2" : "=v"(r) : "v"(lo), "v"(hi));
  return r;
}

__device__ __forceinline__ short8 pack8(f32x4 a, f32x4 b) {
  union { uint32_t u[4]; short8 v; } t;
  t.u[0] = cvt_pk_bf16(a[0], a[1]);
  t.u[1] = cvt_pk_bf16(a[2], a[3]);
  t.u[2] = cvt_pk_bf16(b[0], b[1]);
  t.u[3] = cvt_pk_bf16(b[2], b[3]);
  return t.v;
}

// ---------------------------------------------------------------------------
// r18 kernel body (PROVEN, 22.25us) -- MEASUREMENT ROUND: grid = 1280,
// wg = blockIdx.x % 512: tiles computed 2-3x with byte-identical writes
// (benign; r16-proven replay-safe). Purpose: push this dispatch past the
// harness's 39us fill kernels into the rocprof top-5 so we finally see the
// fused kernel's own VALUBusy / occupancy / conflicts / FETCH, plus the
// time-vs-work ratio (2.5x work): ratio<=2.0 => latency-bound,
// ~2.5 => throughput-bound.
// ---------------------------------------------------------------------------
__global__ __launch_bounds__(512, 4) void dis_att_fused(
    const float* __restrict__ attn, const int* __restrict__ bseq,
    const int* __restrict__ cseq, const float* __restrict__ epos,
    const float* __restrict__ ebi, const float* __restrict__ ebj,
    const float* __restrict__ eci, const float* __restrict__ ecj,
    const float* __restrict__ w1, const float* __restrict__ w2,
    const float* __restrict__ w3, float* __restrict__ out) {
  __shared__ float sW1[96][33];
  __shared__ float sAp[128][36];
  __shared__ float sAi[64][36];
  __shared__ float sAj[64][36];
  int tid = threadIdx.x;
  int wg = blockIdx.x % 512;               // 512 = b(4) h(8) mt(4) nt(4)
  int nt = wg & 3, mt = (wg >> 2) & 3, h = (wg >> 4) & 7, b = wg >> 7;
  int m0 = mt * 64, n0 = nt * 64;
  int f0 = m0 - n0 + 193;                  // global f of sAp row 0
  int lane = tid & 63, w = tid >> 6;
  int lcol = lane & 15, kb = lane >> 4, k8 = kb * 8;
  f32x4 zero = {0.f, 0.f, 0.f, 0.f};

  // ---------------- phase 0: coalesced staging ----------------
#pragma unroll
  for (int i = 0; i < 6; ++i) {
    int idx = tid + 512 * i;               // p*32 + k, 3072 total
    sW1[idx >> 5][idx & 31] = w1[(idx >> 5) * 256 + (idx & 31) * 8 + h];
  }
  {
    int r = tid >> 3, q = tid & 7;
#pragma unroll
    for (int p = 0; p < 2; ++p) {
      int row = r + 64 * p;
      int f = f0 + row; if (f > 511) f = 511;
      *(f32x4*)&sAp[row][q * 4] = *(const f32x4*)(epos + (f * NH + h) * 32 + q * 4);
    }
    int gmi = b * SEQ + m0 + r, gmj = b * SEQ + n0 + r;
    if (q < 4) {
      int bi = bseq[gmi], bj = bseq[gmj];
      *(f32x4*)&sAi[r][q * 4] = *(const f32x4*)(ebi + (bi * NH + h) * 16 + q * 4);
      *(f32x4*)&sAj[r][q * 4] = *(const f32x4*)(ebj + (bj * NH + h) * 16 + q * 4);
    } else {
      int ci = cseq[gmi], cj = cseq[gmj];
      *(f32x4*)&sAi[r][q * 4] = *(const f32x4*)(eci + (ci * NH + h) * 16 + (q - 4) * 4);
      *(f32x4*)&sAj[r][q * 4] = *(const f32x4*)(ecj + (cj * NH + h) * 16 + (q - 4) * 4);
    }
  }
  __syncthreads();

  // ---------------- phase 1a: fragment reads (LDS -> regs) ----------------
  short8 af[2], bf[2];
  if (w < 4) {                             // Apos: tiles {w, w+4}
#pragma unroll
    for (int kt = 0; kt < 2; ++kt) {
      union { uint32_t u[4]; short8 v; } t;
#pragma unroll
      for (int r = 0; r < 4; ++r)
        t.u[r] = cvt_pk_bf16(sW1[k8 + 2 * r][kt * 16 + lcol],
                             sW1[k8 + 2 * r + 1][kt * 16 + lcol]);
      bf[kt] = t.v;
    }
#pragma unroll
    for (int t = 0; t < 2; ++t) {
      int row = (w + t * 4) * 16 + lcol;
      af[t] = pack8(*(const f32x4*)&sAp[row][k8],
                    *(const f32x4*)&sAp[row][k8 + 4]);
    }
  } else {                                 // Ai (waves 4,5) / Aj (waves 6,7)
    int isI = w < 6;
    int p0 = isI ? ((kb < 2 ? 32 : 48) + k8)
                 : ((kb < 2 ? 48 : 64) + k8);
#pragma unroll
    for (int kt = 0; kt < 2; ++kt) {
      union { uint32_t u[4]; short8 v; } t;
#pragma unroll
      for (int r = 0; r < 4; ++r)
        t.u[r] = cvt_pk_bf16(sW1[p0 + 2 * r][kt * 16 + lcol],
                             sW1[p0 + 2 * r + 1][kt * 16 + lcol]);
      bf[kt] = t.v;
    }
    int w2_ = isI ? (w - 4) : (w - 6);
#pragma unroll
    for (int t = 0; t < 2; ++t) {
      int row = (w2_ * 2 + t) * 16 + lcol;
      const float* base = isI ? &sAi[row][0] : &sAj[row][0];
      af[t] = pack8(*(const f32x4*)(base + k8), *(const f32x4*)(base + k8 + 4));
    }
  }
  __syncthreads();                         // all raw reads done

  // ---------------- phase 1b: MFMA + in-place writes ----------------
#pragma unroll
  for (int t = 0; t < 2; ++t) {
#pragma unroll
    for (int kt = 0; kt < 2; ++kt) {
      f32x4 d = __builtin_amdgcn_mfma_f32_16x16x32_bf16(af[t], bf[kt], zero, 0, 0, 0);
      if (w < 4) {
        int mt_ = w + t * 4;
#pragma unroll
        for (int r = 0; r < 4; ++r)
          sAp[mt_ * 16 + kb * 4 + r][kt * 16 + lcol] = d[r];
      } else {
        int isI = w < 6;
        int mt_ = (isI ? (w - 4) : (w - 6)) * 2 + t;
#pragma unroll
        for (int r = 0; r < 4; ++r) {
          float* T = isI ? &sAi[mt_ * 16 + kb * 4 + r][kt * 16 + lcol]
                         : &sAj[mt_ * 16 + kb * 4 + r][kt * 16 + lcol];
          *T = d[r];
        }
      }
    }
  }
  __syncthreads();

  // ---------------- phase 2: main compute (validated r7/r12) ----------------
  union { uint32_t u[4]; short8 v; } w2f;  // A = w2^T: row=lcol, k=k8..k8+7
#pragma unroll
  for (int r = 0; r < 4; ++r) {
    float lo = w2[(k8 + 2 * r) * 128 + lcol * 8 + h];
    float hi = w2[(k8 + 2 * r + 1) * 128 + lcol * 8 + h];
    w2f.u[r] = cvt_pk_bf16(lo, hi);
  }
  float w3v[4];
#pragma unroll
  for (int r = 0; r < 4; ++r) w3v[r] = w3[(kb * 4 + r) * 8 + h];

  f32x4 ajA[4], ajB[4];
#pragma unroll
  for (int ng = 0; ng < 4; ++ng) {
    int nl = ng * 16 + lcol;
    ajA[ng] = *(const f32x4*)&sAj[nl][k8];
    ajB[ng] = *(const f32x4*)&sAj[nl][k8 + 4];
  }

  const float* attn_b = attn + (b * NH + h) * SEQ * SEQ;
  float* out_b = out + (b * NH + h) * SEQ * SEQ;
  int bit4 = kb & 1, bit5 = kb & 2;

#pragma unroll
  for (int s = 0; s < 2; ++s) {
    int mb = w * 8 + s * 4;
    float av[4];
    int idxs[4];
#pragma unroll
    for (int ng = 0; ng < 4; ++ng) {
      idxs[ng] = (m0 + mb + kb) * SEQ + n0 + ng * 16 + lcol;
      av[ng] = attn_b[idxs[ng]];
    }
    f32x4 aiA[4], aiB[4];
#pragma unroll
    for (int mi = 0; mi < 4; ++mi) {
      aiA[mi] = *(const f32x4*)&sAi[mb + mi][k8];
      aiB[mi] = *(const f32x4*)&sAi[mb + mi][k8 + 4];
    }
#pragma unroll
    for (int ng = 0; ng < 4; ++ng) {
      int nl = ng * 16 + lcol;
      f32x4 pA[4], pB[4];
#pragma unroll
      for (int mi = 0; mi < 4; ++mi) {
        int rl = mb + mi - nl + 63;
        pA[mi] = *(const f32x4*)&sAp[rl][k8];
        pB[mi] = *(const f32x4*)&sAp[rl][k8 + 4];
      }
      __builtin_amdgcn_sched_barrier(0);
      float part[4];
#pragma unroll
      for (int mi = 0; mi < 4; ++mi) {
        f32x4 s0 = pA[mi] + aiA[mi] + ajA[ng];
        f32x4 s1 = pB[mi] + aiB[mi] + ajB[ng];
        union { uint32_t u[4]; short8 v; } ef;
        ef.u[0] = cvt_pk_bf16(fmaxf(s0[0], 0.f), fmaxf(s0[1], 0.f));
        ef.u[1] = cvt_pk_bf16(fmaxf(s0[2], 0.f), fmaxf(s0[3], 0.f));
        ef.u[2] = cvt_pk_bf16(fmaxf(s1[0], 0.f), fmaxf(s1[1], 0.f));
        ef.u[3] = cvt_pk_bf16(fmaxf(s1[2], 0.f), fmaxf(s1[3], 0.f));
        f32x4 d = __builtin_amdgcn_mfma_f32_16x16x32_bf16(w2f.v, ef.v, zero, 0, 0, 0);
        part[mi] = fmaxf(d[0], 0.f) * w3v[0] + fmaxf(d[1], 0.f) * w3v[1] +
                   fmaxf(d[2], 0.f) * w3v[2] + fmaxf(d[3], 0.f) * w3v[3];
      }
      float mineA = bit4 ? part[1] : part[0];
      float sendA = bit4 ? part[0] : part[1];
      float mineB = bit4 ? part[3] : part[2];
      float sendB = bit4 ? part[2] : part[3];
      mineA += __shfl_xor(sendA, 16, 64);
      mineB += __shfl_xor(sendB, 16, 64);
      float keep = bit5 ? mineB : mineA;
      float send = bit5 ? mineA : mineB;
      float res = keep + __shfl_xor(send, 32, 64);
      out_b[idxs[ng]] = av[ng] + res;
    }
  }
}

extern "C" void kernel_launch(void* const* d_in, const int* in_sizes, int n_in,
                              void* d_out, int out_size, void* d_ws, size_t ws_size,
                              hipStream_t stream) {
  const float* attn = (const float*)d_in[0];
  const int* bseq   = (const int*)d_in[1];
  const int* cseq   = (const int*)d_in[2];
  const float* epos = (const float*)d_in[3];
  const float* ebi  = (const float*)d_in[4];
  const float* ebj  = (const float*)d_in[5];
  const float* eci  = (const float*)d_in[6];
  const float* ecj  = (const float*)d_in[7];
  const float* w1   = (const float*)d_in[8];
  const float* w2   = (const float*)d_in[9];
  const float* w3   = (const float*)d_in[10];
  float* out = (float*)d_out;

  hipLaunchKernelGGL(dis_att_fused, dim3(1280), dim3(512), 0, stream,
                     attn, bseq, cseq, epos, ebi, ebj, eci, ecj, w1, w2, w3, out);
}

// Round 21
// 25.086 us; speedup vs baseline: 1.5933x; 1.5933x over previous
//
#include <hip/hip_runtime.h>
#include <stdint.h>

typedef __attribute__((ext_vector_type(8))) short short8;
typedef __attribute__((ext_vector_type(8))) _Float16 half8;
typedef __attribute__((ext_vector_type(4))) float f32x4;
typedef __attribute__((ext_vector_type(4))) uint32_t u32x4;
typedef __attribute__((ext_vector_type(2))) uint32_t u32x2;

#define SEQ 256
#define NH 8

__device__ __forceinline__ uint32_t cvt_pk_bf16(float lo, float hi) {
  uint32_t r;
  asm("v_cvt_pk_bf16_f32 %0, %1, %2" : "=v"(r) : "v"(lo), "v"(hi));
  return r;
}
__device__ __forceinline__ uint32_t cvt_pk_f16(float lo, float hi) {
  uint32_t r;
  asm("v_cvt_pkrtz_f16_f32 %0, %1, %2" : "=v"(r) : "v"(lo), "v"(hi));
  return r;
}
__device__ __forceinline__ uint32_t pk_add(uint32_t a, uint32_t b) {
  uint32_t r;
  asm("v_pk_add_f16 %0, %1, %2" : "=v"(r) : "v"(a), "v"(b));
  return r;
}
__device__ __forceinline__ uint32_t pk_relu(uint32_t a) {
  uint32_t r;
  asm("v_pk_max_f16 %0, %1, 0" : "=v"(r) : "v"(a));
  return r;
}

// ---------------------------------------------------------------------------
// ONE fused kernel, LDS-diet + packed pipeline.
// Block = (b, h, 64m x 64n), 512 thr (8 waves), 512 blocks, LDS 26.2 KB,
// launch_bounds(512,8) caps VGPR at 64 -> 4 blocks/CU (2x r20's residency).
// Phase 0: stage PRE-PACKED bf16 pairs (cvt at stage, r15-proven):
//   sW1p[48][33]u32 (w1 pairs along p), tAp[128][20] raw epos band,
//   tAi/tAj[64][20] raw emb rows ([ebi|eci] / [ebj|ecj]).
// Phase 1a: fragments = single u32x4 / scalar u32 LDS reads -- values
//   bit-identical to r18's proven fragments. barrier.
// Phase 1b: bf16 MFMA (r5-proven conventions); D pairs packed ACROSS lanes
//   (shfl_xor(d,1), even-lcol lanes cvt_pk_f16 + write) IN-PLACE over the
//   raw buffers -> packed f16 tables [row][k_out pair].
// Phase 2: r15-PROVEN packed path: 4x ds_read_b128/group, pk_add/pk_max
//   e1, f16 MFMA (A=w2^T f16), relu-dot w3, butterfly, attn-add store.
// ---------------------------------------------------------------------------
__global__ __launch_bounds__(512, 8) void dis_att_fused(
    const float* __restrict__ attn, const int* __restrict__ bseq,
    const int* __restrict__ cseq, const float* __restrict__ epos,
    const float* __restrict__ ebi, const float* __restrict__ ebj,
    const float* __restrict__ eci, const float* __restrict__ ecj,
    const float* __restrict__ w1, const float* __restrict__ w2,
    const float* __restrict__ w3, float* __restrict__ out) {
  __shared__ uint32_t sW1p[48][33];   // 6.3 KB
  __shared__ uint32_t tAp[128][20];   // 10.2 KB raw bf16 -> packed f16
  __shared__ uint32_t tAi[64][20];    //  5.1 KB
  __shared__ uint32_t tAj[64][20];    //  5.1 KB  total 26.2 KB
  int tid = threadIdx.x;
  int wg = blockIdx.x;                     // 512 = b(4) h(8) mt(4) nt(4)
  int nt = wg & 3, mt = (wg >> 2) & 3, h = (wg >> 4) & 7, b = wg >> 7;
  int m0 = mt * 64, n0 = nt * 64;
  int f0 = m0 - n0 + 193;                  // global f of band row 0
  int lane = tid & 63, w = tid >> 6;
  int lcol = lane & 15, kb = lane >> 4, k8 = kb * 8, kq = kb * 4;
  f32x4 zero = {0.f, 0.f, 0.f, 0.f};

  // ---------------- phase 0: pre-packed staging ----------------
#pragma unroll
  for (int i = 0; i < 3; ++i) {
    int idx = tid + 512 * i;               // 1536 = 48 pp x 32 c
    int pp = idx >> 5, c = idx & 31;
    sW1p[pp][c] = cvt_pk_bf16(w1[(2 * pp) * 256 + c * 8 + h],
                              w1[(2 * pp + 1) * 256 + c * 8 + h]);
  }
  {
    int r = tid >> 3, q = tid & 7;
#pragma unroll
    for (int p = 0; p < 2; ++p) {
      int row = r + 64 * p;
      int f = f0 + row; if (f > 511) f = 511;   // row 127 junk, never read
      f32x4 v = *(const f32x4*)(epos + (f * NH + h) * 32 + q * 4);
      u32x2 o = {cvt_pk_bf16(v[0], v[1]), cvt_pk_bf16(v[2], v[3])};
      *(u32x2*)&tAp[row][q * 2] = o;
    }
    int gmi = b * SEQ + m0 + r, gmj = b * SEQ + n0 + r;
    if (q < 4) {
      int bi = bseq[gmi], bj = bseq[gmj];
      f32x4 vi = *(const f32x4*)(ebi + (bi * NH + h) * 16 + q * 4);
      f32x4 vj = *(const f32x4*)(ebj + (bj * NH + h) * 16 + q * 4);
      u32x2 oi = {cvt_pk_bf16(vi[0], vi[1]), cvt_pk_bf16(vi[2], vi[3])};
      u32x2 oj = {cvt_pk_bf16(vj[0], vj[1]), cvt_pk_bf16(vj[2], vj[3])};
      *(u32x2*)&tAi[r][q * 2] = oi;
      *(u32x2*)&tAj[r][q * 2] = oj;
    } else {
      int ci = cseq[gmi], cj = cseq[gmj];
      f32x4 vi = *(const f32x4*)(eci + (ci * NH + h) * 16 + (q - 4) * 4);
      f32x4 vj = *(const f32x4*)(ecj + (cj * NH + h) * 16 + (q - 4) * 4);
      u32x2 oi = {cvt_pk_bf16(vi[0], vi[1]), cvt_pk_bf16(vi[2], vi[3])};
      u32x2 oj = {cvt_pk_bf16(vj[0], vj[1]), cvt_pk_bf16(vj[2], vj[3])};
      *(u32x2*)&tAi[r][8 + (q - 4) * 2] = oi;
      *(u32x2*)&tAj[r][8 + (q - 4) * 2] = oj;
    }
  }
  __syncthreads();

  // ---------------- phase 1a: fragment reads (values == r18) ----------------
  int isI = w < 6;
  int w2_ = isI ? (w - 4) : (w - 6);
  // p0h = p0/2: pos k8/2; i: rows 32..47|64..79; j: rows 48..63|80..95
  int p0h = (w < 4) ? kq
                    : (isI ? ((kb < 2 ? 16 : 24) + kq)
                           : ((kb < 2 ? 24 : 32) + kq));
  short8 af[2], bf[2];
#pragma unroll
  for (int kt = 0; kt < 2; ++kt) {
    union { uint32_t u[4]; short8 v; } t;
#pragma unroll
    for (int r = 0; r < 4; ++r) t.u[r] = sW1p[p0h + r][kt * 16 + lcol];
    bf[kt] = t.v;
  }
#pragma unroll
  for (int t = 0; t < 2; ++t) {
    int row = ((w < 4) ? (w + t * 4) : (w2_ * 2 + t)) * 16 + lcol;
    const uint32_t* base = (w < 4) ? &tAp[row][0]
                                   : (isI ? &tAi[row][0] : &tAj[row][0]);
    union { u32x4 u; short8 v; } t2;
    t2.u = *(const u32x4*)(base + kq);
    af[t] = t2.v;
  }
  __syncthreads();                         // all raw reads in regs

  // ---------------- phase 1b: MFMA + cross-lane f16 pack, in-place ---------
#pragma unroll
  for (int t = 0; t < 2; ++t) {
    int row_base = ((w < 4) ? (w + t * 4) : (w2_ * 2 + t)) * 16;
#pragma unroll
    for (int kt = 0; kt < 2; ++kt) {
      f32x4 d = __builtin_amdgcn_mfma_f32_16x16x32_bf16(af[t], bf[kt], zero, 0, 0, 0);
      f32x4 dn;
#pragma unroll
      for (int r = 0; r < 4; ++r) dn[r] = __shfl_xor(d[r], 1, 64);
      if ((lcol & 1) == 0) {               // even col packs (col, col+1)
        int pcol = kt * 8 + (lcol >> 1);
#pragma unroll
        for (int r = 0; r < 4; ++r) {
          uint32_t pk = cvt_pk_f16(d[r], dn[r]);
          int prow = row_base + kb * 4 + r;
          if (w < 4)    tAp[prow][pcol] = pk;
          else if (isI) tAi[prow][pcol] = pk;
          else          tAj[prow][pcol] = pk;
        }
      }
    }
  }
  __syncthreads();

  // ---------------- phase 2: packed main compute (r15-proven) ----------
  union { uint32_t u[4]; half8 v; } w2f;   // A = w2^T (f16): row=lcol
#pragma unroll
  for (int r = 0; r < 4; ++r) {
    float lo = w2[(k8 + 2 * r) * 128 + lcol * 8 + h];
    float hi = w2[(k8 + 2 * r + 1) * 128 + lcol * 8 + h];
    w2f.u[r] = cvt_pk_f16(lo, hi);
  }
  float w3v[4];
#pragma unroll
  for (int r = 0; r < 4; ++r) w3v[r] = w3[(kb * 4 + r) * 8 + h];

  u32x4 ajP[4];
#pragma unroll
  for (int ng = 0; ng < 4; ++ng)
    ajP[ng] = *(const u32x4*)&tAj[ng * 16 + lcol][kq];

  const float* attn_b = attn + (b * NH + h) * SEQ * SEQ;
  float* out_b = out + (b * NH + h) * SEQ * SEQ;
  int bit4 = kb & 1, bit5 = kb & 2;

#pragma unroll
  for (int s = 0; s < 2; ++s) {
    int mb = w * 8 + s * 4;
    float av[4];
    int idxs[4];
#pragma unroll
    for (int ng = 0; ng < 4; ++ng) {
      idxs[ng] = (m0 + mb + kb) * SEQ + n0 + ng * 16 + lcol;
      av[ng] = attn_b[idxs[ng]];
    }
    u32x4 aiP[4];
#pragma unroll
    for (int mi = 0; mi < 4; ++mi)
      aiP[mi] = *(const u32x4*)&tAi[mb + mi][kq];
#pragma unroll
    for (int ng = 0; ng < 4; ++ng) {
      int nl = ng * 16 + lcol;
      u32x4 pP[4];
#pragma unroll
      for (int mi = 0; mi < 4; ++mi)
        pP[mi] = *(const u32x4*)&tAp[mb + mi - nl + 63][kq];
      __builtin_amdgcn_sched_barrier(0);
      float part[4];
#pragma unroll
      for (int mi = 0; mi < 4; ++mi) {
        union { uint32_t u[4]; half8 v; } ef;
#pragma unroll
        for (int r = 0; r < 4; ++r)
          ef.u[r] = pk_relu(pk_add(pk_add(pP[mi][r], aiP[mi][r]), ajP[ng][r]));
        f32x4 d = __builtin_amdgcn_mfma_f32_16x16x32_f16(w2f.v, ef.v, zero, 0, 0, 0);
        part[mi] = fmaxf(d[0], 0.f) * w3v[0] + fmaxf(d[1], 0.f) * w3v[1] +
                   fmaxf(d[2], 0.f) * w3v[2] + fmaxf(d[3], 0.f) * w3v[3];
      }
      float mineA = bit4 ? part[1] : part[0];
      float sendA = bit4 ? part[0] : part[1];
      float mineB = bit4 ? part[3] : part[2];
      float sendB = bit4 ? part[2] : part[3];
      mineA += __shfl_xor(sendA, 16, 64);
      mineB += __shfl_xor(sendB, 16, 64);
      float keep = bit5 ? mineB : mineA;
      float send = bit5 ? mineA : mineB;
      float res = keep + __shfl_xor(send, 32, 64);
      out_b[idxs[ng]] = av[ng] + res;
    }
  }
}

extern "C" void kernel_launch(void* const* d_in, const int* in_sizes, int n_in,
                              void* d_out, int out_size, void* d_ws, size_t ws_size,
                              hipStream_t stream) {
  const float* attn = (const float*)d_in[0];
  const int* bseq   = (const int*)d_in[1];
  const int* cseq   = (const int*)d_in[2];
  const float* epos = (const float*)d_in[3];
  const float* ebi  = (const float*)d_in[4];
  const float* ebj  = (const float*)d_in[5];
  const float* eci  = (const float*)d_in[6];
  const float* ecj  = (const float*)d_in[7];
  const float* w1   = (const float*)d_in[8];
  const float* w2   = (const float*)d_in[9];
  const float* w3   = (const float*)d_in[10];
  float* out = (float*)d_out;

  hipLaunchKernelGGL(dis_att_fused, dim3(512), dim3(512), 0, stream,
                     attn, bseq, cseq, epos, ebi, ebj, eci, ecj, w1, w2, w3, out);
}